// Round 4
// baseline (280.602 us; speedup 1.0000x reference)
//
#include <hip/hip_runtime.h>
#include <cstdint>
#include <cstddef>

#define B_  64
#define D_  128
#define LC_ 1024
#define LQ_ 128
#define NEGV (-1e30f)
#define NINF (-3.402823466e38f)

typedef short s16x8 __attribute__((ext_vector_type(8)));
typedef float f32x4 __attribute__((ext_vector_type(4)));

__device__ __forceinline__ unsigned short f2bf(float x) {
    union { float f; unsigned u; } v; v.f = x;
    unsigned r = v.u + 0x7fffu + ((v.u >> 16) & 1u);   // RNE
    return (unsigned short)(r >> 16);
}
__device__ __forceinline__ float bf2f(unsigned short x) {
    union { unsigned u; float f; } v; v.u = ((unsigned)x) << 16;
    return v.f;
}

// bank swizzle for fp32 epilogue tile (stride 132 dw)
#define SW(r, c) ((c) ^ (((r) & 7) << 2))

// ---------------------------------------------------------------------------
// kT_C: CWt[b][c][d] = bf16(w_m[d]*C[b][d][c]) ; Cb[b][d][c] = bf16(C) ;
//       sc[b][c] = sum_d C*w_c
// ---------------------------------------------------------------------------
__global__ __launch_bounds__(256) void kT_C(const float* __restrict__ C,
                                            const float* __restrict__ w,
                                            unsigned short* __restrict__ CWt,
                                            unsigned short* __restrict__ Cb,
                                            float* __restrict__ sc_g) {
    __shared__ float tile[32][33];
    __shared__ float wc_l[128], wm_l[128];
    __shared__ float red[8][32];
    int t = threadIdx.x;
    int b = blockIdx.y, c0 = blockIdx.x * 32;
    if (t < 128) { wc_l[t] = w[D_ + t]; wm_l[t] = w[2 * D_ + t]; }
    __syncthreads();
    float scp = 0.f;
    int cc = t & 31, db = t >> 5;
    for (int ch = 0; ch < 4; ch++) {
#pragma unroll
        for (int i = 0; i < 4; i++) {
            int dl = db * 4 + i;
            float v = C[((size_t)(b * D_ + ch * 32 + dl)) * LC_ + c0 + cc];
            tile[dl][cc] = v;
            scp += v * wc_l[ch * 32 + dl];
        }
        __syncthreads();
        {
            int c2 = t >> 3, ds = (t & 7) * 4;
            ushort4 o;
            o.x = f2bf(tile[ds + 0][c2] * wm_l[ch * 32 + ds + 0]);
            o.y = f2bf(tile[ds + 1][c2] * wm_l[ch * 32 + ds + 1]);
            o.z = f2bf(tile[ds + 2][c2] * wm_l[ch * 32 + ds + 2]);
            o.w = f2bf(tile[ds + 3][c2] * wm_l[ch * 32 + ds + 3]);
            *(ushort4*)&CWt[((size_t)(b * LC_ + c0 + c2)) * D_ + ch * 32 + ds] = o;
        }
        {
            int d2 = t >> 3, cs = (t & 7) * 4;
            ushort4 o;
            o.x = f2bf(tile[d2][cs + 0]);
            o.y = f2bf(tile[d2][cs + 1]);
            o.z = f2bf(tile[d2][cs + 2]);
            o.w = f2bf(tile[d2][cs + 3]);
            *(ushort4*)&Cb[((size_t)(b * D_ + ch * 32 + d2)) * LC_ + c0 + cs] = o;
        }
        __syncthreads();
    }
    red[db][cc] = scp;
    __syncthreads();
    if (t < 32) {
        float s = 0.f;
#pragma unroll
        for (int j = 0; j < 8; j++) s += red[j][t];
        sc_g[b * LC_ + c0 + t] = s;
    }
}

// ---------------------------------------------------------------------------
// kT_Q: Qt[b][q][d] = bf16(Q[b][d][q]) ; Qb[b][d][q] = bf16(Q) ; sq = sum Q*w_q
// ---------------------------------------------------------------------------
__global__ __launch_bounds__(256) void kT_Q(const float* __restrict__ Q,
                                            const float* __restrict__ w,
                                            unsigned short* __restrict__ Qt,
                                            unsigned short* __restrict__ Qb,
                                            float* __restrict__ sq_g) {
    __shared__ float tile[32][33];
    __shared__ float wq_l[128];
    __shared__ float red[8][32];
    int t = threadIdx.x;
    int b = blockIdx.y, q0 = blockIdx.x * 32;
    if (t < 128) wq_l[t] = w[t];
    __syncthreads();
    float sqp = 0.f;
    int qq = t & 31, db = t >> 5;
    for (int ch = 0; ch < 4; ch++) {
#pragma unroll
        for (int i = 0; i < 4; i++) {
            int dl = db * 4 + i;
            float v = Q[((size_t)(b * D_ + ch * 32 + dl)) * LQ_ + q0 + qq];
            tile[dl][qq] = v;
            sqp += v * wq_l[ch * 32 + dl];
        }
        __syncthreads();
        {
            int q2 = t >> 3, ds = (t & 7) * 4;
            ushort4 o;
            o.x = f2bf(tile[ds + 0][q2]);
            o.y = f2bf(tile[ds + 1][q2]);
            o.z = f2bf(tile[ds + 2][q2]);
            o.w = f2bf(tile[ds + 3][q2]);
            *(ushort4*)&Qt[((size_t)(b * LQ_ + q0 + q2)) * D_ + ch * 32 + ds] = o;
        }
        {
            int d2 = t >> 3, qs = (t & 7) * 4;
            ushort4 o;
            o.x = f2bf(tile[d2][qs + 0]);
            o.y = f2bf(tile[d2][qs + 1]);
            o.z = f2bf(tile[d2][qs + 2]);
            o.w = f2bf(tile[d2][qs + 3]);
            *(ushort4*)&Qb[((size_t)(b * D_ + ch * 32 + d2)) * LQ_ + q0 + qs] = o;
        }
        __syncthreads();
    }
    red[db][qq] = sqp;
    __syncthreads();
    if (t < 32) {
        float s = 0.f;
#pragma unroll
        for (int j = 0; j < 8; j++) s += red[j][t];
        sq_g[b * LQ_ + q0 + t] = s;
    }
}

// ---------------------------------------------------------------------------
// kA_S: S tile via MFMA; fused row softmax -> S1b[c][q] bf16;
// fused g-scaled transpose -> S1Et[q][c] bf16 (= S1*g, g=rowsum*exp(rowmax+cmv));
// column partial stats -> pmax/psum.
// grid (LC/128, B), 256 thr
// ---------------------------------------------------------------------------
__global__ __launch_bounds__(256) void kA_S(const unsigned short* __restrict__ CWt,
                                            const unsigned short* __restrict__ Qt,
                                            const float* __restrict__ sc_g,
                                            const float* __restrict__ sq_g,
                                            const float* __restrict__ cmask,
                                            const float* __restrict__ qmask,
                                            unsigned short* __restrict__ S1b,
                                            unsigned short* __restrict__ S1Et,
                                            float* __restrict__ pmax_g,
                                            float* __restrict__ psum_g) {
    __shared__ unsigned short Tt[128 * 136];
    __shared__ float sc_l[128], sq_l[128], cmv_l[128], qmv_l[128], gs[128];
    int t = threadIdx.x;
    int b = blockIdx.y, c0 = blockIdx.x * 128;
    if (t < 128) {
        sc_l[t] = sc_g[b * LC_ + c0 + t];
        sq_l[t] = sq_g[b * LQ_ + t];
        cmv_l[t] = (1.0f - cmask[b * LC_ + c0 + t]) * NEGV;
        qmv_l[t] = (1.0f - qmask[b * LQ_ + t]) * NEGV;
    }
    __syncthreads();
    int wv = t >> 6, l = t & 63, quad = l >> 4, lp = l & 15;
    int w32 = wv * 32;
    f32x4 zero = {0.f, 0.f, 0.f, 0.f};
    f32x4 acc[2][8];
#pragma unroll
    for (int mc = 0; mc < 2; mc++)
#pragma unroll
        for (int qt = 0; qt < 8; qt++) acc[mc][qt] = zero;

#pragma unroll
    for (int ks = 0; ks < 4; ks++) {
        s16x8 a[2], bb[8];
        a[0] = *(const s16x8*)&CWt[((size_t)(b * LC_ + c0 + w32 + lp)) * D_ + ks * 32 + quad * 8];
        a[1] = *(const s16x8*)&CWt[((size_t)(b * LC_ + c0 + w32 + 16 + lp)) * D_ + ks * 32 + quad * 8];
#pragma unroll
        for (int qt = 0; qt < 8; qt++)
            bb[qt] = *(const s16x8*)&Qt[((size_t)(b * LQ_ + qt * 16 + lp)) * D_ + ks * 32 + quad * 8];
#pragma unroll
        for (int mc = 0; mc < 2; mc++)
#pragma unroll
            for (int qt = 0; qt < 8; qt++)
                acc[mc][qt] = __builtin_amdgcn_mfma_f32_16x16x32_bf16(a[mc], bb[qt], acc[mc][qt], 0, 0, 0);
    }
#pragma unroll
    for (int mc = 0; mc < 2; mc++)
#pragma unroll
        for (int qt = 0; qt < 8; qt++)
#pragma unroll
            for (int i = 0; i < 4; i++)
                acc[mc][qt][i] += sc_l[w32 + mc * 16 + quad * 4 + i] + sq_l[qt * 16 + lp];

    float qmv_r[8];
#pragma unroll
    for (int qt = 0; qt < 8; qt++) qmv_r[qt] = qmv_l[qt * 16 + lp];

    // row softmax stats (over q), g for the E2 factorization
    float rm_r[2][4], ri_r[2][4];
#pragma unroll
    for (int mc = 0; mc < 2; mc++)
#pragma unroll
        for (int i = 0; i < 4; i++) {
            float m = NINF;
#pragma unroll
            for (int qt = 0; qt < 8; qt++) m = fmaxf(m, acc[mc][qt][i] + qmv_r[qt]);
#pragma unroll
            for (int off = 1; off < 16; off <<= 1) m = fmaxf(m, __shfl_xor(m, off, 64));
            float s = 0.f;
#pragma unroll
            for (int qt = 0; qt < 8; qt++) s += __expf(acc[mc][qt][i] + qmv_r[qt] - m);
#pragma unroll
            for (int off = 1; off < 16; off <<= 1) s += __shfl_xor(s, off, 64);
            rm_r[mc][i] = m;
            ri_r[mc][i] = 1.0f / s;
            int row = w32 + mc * 16 + quad * 4 + i;
            if (lp == 0) gs[row] = s * __expf(m + cmv_l[row]);
        }

    // column partial stats over this wave's 32 rows
    float cmv_r[2][4];
#pragma unroll
    for (int mc = 0; mc < 2; mc++)
#pragma unroll
        for (int i = 0; i < 4; i++) cmv_r[mc][i] = cmv_l[w32 + mc * 16 + quad * 4 + i];
    int chunk = blockIdx.x * 4 + wv;
#pragma unroll
    for (int qt = 0; qt < 8; qt++) {
        float cm = NINF;
#pragma unroll
        for (int mc = 0; mc < 2; mc++)
#pragma unroll
            for (int i = 0; i < 4; i++) cm = fmaxf(cm, acc[mc][qt][i] + cmv_r[mc][i]);
        cm = fmaxf(cm, __shfl_xor(cm, 16, 64));
        cm = fmaxf(cm, __shfl_xor(cm, 32, 64));
        float cs = 0.f;
#pragma unroll
        for (int mc = 0; mc < 2; mc++)
#pragma unroll
            for (int i = 0; i < 4; i++) cs += __expf(acc[mc][qt][i] + cmv_r[mc][i] - cm);
        cs += __shfl_xor(cs, 16, 64);
        cs += __shfl_xor(cs, 32, 64);
        if (l < 16) {
            pmax_g[((size_t)(b * 32 + chunk)) * LQ_ + qt * 16 + lp] = cm;
            psum_g[((size_t)(b * 32 + chunk)) * LQ_ + qt * 16 + lp] = cs;
        }
    }

    // S1 -> LDS tile [c][q]
#pragma unroll
    for (int mc = 0; mc < 2; mc++)
#pragma unroll
        for (int qt = 0; qt < 8; qt++)
#pragma unroll
            for (int i = 0; i < 4; i++) {
                int row = w32 + mc * 16 + quad * 4 + i;
                float s1 = __expf(acc[mc][qt][i] + qmv_r[qt] - rm_r[mc][i]) * ri_r[mc][i];
                Tt[row * 136 + qt * 16 + lp] = f2bf(s1);
            }
    __syncthreads();
    // S1b [c][q] coalesced
    {
        int row = t >> 1, qh = (t & 1) * 64;
        const uint4* src = (const uint4*)&Tt[row * 136 + qh];
        uint4* dst = (uint4*)&S1b[((size_t)(b * LC_ + c0 + row)) * LQ_ + qh];
#pragma unroll
        for (int j = 0; j < 8; j++) dst[j] = src[j];
    }
    // S1Et [q][c] = S1 * g[c], coalesced along c
    {
        int r4 = t >> 2;              // 0..63
        int cq = (t & 3) * 8;         // 0,8,16,24
#pragma unroll
        for (int qh = 0; qh < 2; qh++) {
            int q = qh * 64 + r4;
#pragma unroll
            for (int j = 0; j < 4; j++) {
                int c = j * 32 + cq;
                uint4 pk;
                unsigned short* po = (unsigned short*)&pk;
#pragma unroll
                for (int k = 0; k < 8; k++)
                    po[k] = f2bf(bf2f(Tt[(c + k) * 136 + q]) * gs[c + k]);
                *(uint4*)&S1Et[((size_t)(b * LQ_ + q)) * LC_ + c0 + c] = pk;
            }
        }
    }
}

// ---------------------------------------------------------------------------
// k2b: reduce 32 col-partial chunks -> hq = exp(-colmax), ci = 1/colsum
// ---------------------------------------------------------------------------
__global__ __launch_bounds__(128) void k2b(const float* __restrict__ pmax,
                                           const float* __restrict__ psum,
                                           float* __restrict__ hq_g,
                                           float* __restrict__ ci_g) {
    int q = threadIdx.x, b = blockIdx.x;
    float m = NINF;
    for (int j = 0; j < 32; j++) m = fmaxf(m, pmax[((size_t)(b * 32 + j)) * LQ_ + q]);
    float s = 0.f;
    for (int j = 0; j < 32; j++)
        s += psum[((size_t)(b * 32 + j)) * LQ_ + q] * __expf(pmax[((size_t)(b * 32 + j)) * LQ_ + q] - m);
    hq_g[b * LQ_ + q] = __expf(-m);
    ci_g[b * LQ_ + q] = 1.0f / s;
}

// ---------------------------------------------------------------------------
// kB_T2: pure LDS-free bf16 GEMM. T2p[kc][b][d][q] = sum_{c chunk} Cb[d][c]*S1Et[q][c]
// grid (8 K-splits, B), 256 thr
// ---------------------------------------------------------------------------
__global__ __launch_bounds__(256) void kB_T2(const unsigned short* __restrict__ Cb,
                                             const unsigned short* __restrict__ S1Et,
                                             float* __restrict__ T2p) {
    int t = threadIdx.x;
    int b = blockIdx.y, kc = blockIdx.x;
    int cbase = kc * 128;
    int wv = t >> 6, l = t & 63, quad = l >> 4, lp = l & 15;
    int w32 = wv * 32;
    f32x4 zero = {0.f, 0.f, 0.f, 0.f};
    f32x4 acc[2][8];
#pragma unroll
    for (int mc = 0; mc < 2; mc++)
#pragma unroll
        for (int nt = 0; nt < 8; nt++) acc[mc][nt] = zero;

#pragma unroll
    for (int ks = 0; ks < 4; ks++) {
        s16x8 a[2], bb[8];
        a[0] = *(const s16x8*)&Cb[((size_t)(b * D_ + w32 + lp)) * LC_ + cbase + ks * 32 + quad * 8];
        a[1] = *(const s16x8*)&Cb[((size_t)(b * D_ + w32 + 16 + lp)) * LC_ + cbase + ks * 32 + quad * 8];
#pragma unroll
        for (int nt = 0; nt < 8; nt++)
            bb[nt] = *(const s16x8*)&S1Et[((size_t)(b * LQ_ + nt * 16 + lp)) * LC_ + cbase + ks * 32 + quad * 8];
#pragma unroll
        for (int mc = 0; mc < 2; mc++)
#pragma unroll
            for (int nt = 0; nt < 8; nt++)
                acc[mc][nt] = __builtin_amdgcn_mfma_f32_16x16x32_bf16(a[mc], bb[nt], acc[mc][nt], 0, 0, 0);
    }
#pragma unroll
    for (int mc = 0; mc < 2; mc++)
#pragma unroll
        for (int i = 0; i < 4; i++) {
            int d = w32 + mc * 16 + quad * 4 + i;
#pragma unroll
            for (int nt = 0; nt < 8; nt++)
                T2p[(((size_t)kc * B_ + b) * D_ + d) * LQ_ + nt * 16 + lp] = acc[mc][nt][i];
        }
}

// ---------------------------------------------------------------------------
// k3b: T2b bf16 = (sum of 8 K-split partials) * hq[q] * ci[q]
// ---------------------------------------------------------------------------
__global__ __launch_bounds__(256) void k3b(const float* __restrict__ T2p,
                                           const float* __restrict__ hq_g,
                                           const float* __restrict__ ci_g,
                                           unsigned short* __restrict__ T2b) {
    int idx = blockIdx.x * 256 + threadIdx.x;
    const size_t N = (size_t)B_ * D_ * LQ_;
    int b = idx >> 14, q = idx & 127;
    float s = 0.f;
#pragma unroll
    for (int j = 0; j < 8; j++) s += T2p[idx + j * N];
    T2b[idx] = f2bf(s * hq_g[b * LQ_ + q] * ci_g[b * LQ_ + q]);
}

// ---------------------------------------------------------------------------
// kC_out: accA = S1·Q^T, accB = S1·T2^T (LDS-free MFMA loop); epilogue goes
// through a swizzled fp32 LDS tile so all 134 MB of output is dwordx4 stores.
// grid (LC/128, B), 256 thr
// ---------------------------------------------------------------------------
__global__ __launch_bounds__(256) void kC_out(const float* __restrict__ C,
                                              const unsigned short* __restrict__ Qb,
                                              const unsigned short* __restrict__ T2b,
                                              const unsigned short* __restrict__ S1b,
                                              float* __restrict__ out) {
    __shared__ float Tile[64 * 132];   // 33.8 KB
    int t = threadIdx.x;
    int b = blockIdx.y, c0 = blockIdx.x * 128;
    int wv = t >> 6, l = t & 63, quad = l >> 4, lp = l & 15;
    int w32 = wv * 32;
    f32x4 zero = {0.f, 0.f, 0.f, 0.f};
    f32x4 accA[2][8], accB[2][8];
#pragma unroll
    for (int mc = 0; mc < 2; mc++)
#pragma unroll
        for (int nt = 0; nt < 8; nt++) { accA[mc][nt] = zero; accB[mc][nt] = zero; }

#pragma unroll
    for (int ks = 0; ks < 4; ks++) {
        s16x8 aq[2], at[2], bb[8];
        aq[0] = *(const s16x8*)&Qb[((size_t)(b * D_ + w32 + lp)) * LQ_ + ks * 32 + quad * 8];
        aq[1] = *(const s16x8*)&Qb[((size_t)(b * D_ + w32 + 16 + lp)) * LQ_ + ks * 32 + quad * 8];
        at[0] = *(const s16x8*)&T2b[((size_t)(b * D_ + w32 + lp)) * LQ_ + ks * 32 + quad * 8];
        at[1] = *(const s16x8*)&T2b[((size_t)(b * D_ + w32 + 16 + lp)) * LQ_ + ks * 32 + quad * 8];
#pragma unroll
        for (int nt = 0; nt < 8; nt++)
            bb[nt] = *(const s16x8*)&S1b[((size_t)(b * LC_ + c0 + nt * 16 + lp)) * LQ_ + ks * 32 + quad * 8];
#pragma unroll
        for (int mc = 0; mc < 2; mc++)
#pragma unroll
            for (int nt = 0; nt < 8; nt++) {
                accA[mc][nt] = __builtin_amdgcn_mfma_f32_16x16x32_bf16(aq[mc], bb[nt], accA[mc][nt], 0, 0, 0);
                accB[mc][nt] = __builtin_amdgcn_mfma_f32_16x16x32_bf16(at[mc], bb[nt], accB[mc][nt], 0, 0, 0);
            }
    }

    const size_t DL = (size_t)D_ * LC_;
    int r = t >> 2;                   // 0..63 (tile row for the store phase)
    int rw = wv * 16;                 // this wave's tile-row base (write phase)
#pragma unroll
    for (int mc = 0; mc < 2; mc++) {
        int d_st = (r >> 4) * 32 + mc * 16 + (r & 15);
        const float* Crow = C + ((size_t)(b * D_ + d_st)) * LC_ + c0;
        size_t ob = ((size_t)(b * 4 * D_ + d_st)) * LC_ + c0;
        // ---- phase A: accA[mc] -> streams 0 (C), 1 (A), 2 (C*A) ----
        __syncthreads();
#pragma unroll
        for (int nt = 0; nt < 8; nt++)
#pragma unroll
            for (int i = 0; i < 4; i++) {
                int row = rw + quad * 4 + i;
                Tile[row * 132 + SW(row, nt * 16 + lp)] = accA[mc][nt][i];
            }
        __syncthreads();
#pragma unroll
        for (int j = 0; j < 8; j++) {
            int c = j * 16 + (t & 3) * 4;
            float4 a4 = *(const float4*)&Tile[r * 132 + SW(r, c)];
            float4 cv = *(const float4*)&Crow[c];
            *(float4*)&out[ob + c] = cv;
            *(float4*)&out[ob + DL + c] = a4;
            float4 ca;
            ca.x = cv.x * a4.x; ca.y = cv.y * a4.y; ca.z = cv.z * a4.z; ca.w = cv.w * a4.w;
            *(float4*)&out[ob + 2 * DL + c] = ca;
        }
        // ---- phase B: accB[mc] -> stream 3 (C*Bt) ----
        __syncthreads();
#pragma unroll
        for (int nt = 0; nt < 8; nt++)
#pragma unroll
            for (int i = 0; i < 4; i++) {
                int row = rw + quad * 4 + i;
                Tile[row * 132 + SW(row, nt * 16 + lp)] = accB[mc][nt][i];
            }
        __syncthreads();
#pragma unroll
        for (int j = 0; j < 8; j++) {
            int c = j * 16 + (t & 3) * 4;
            float4 b4 = *(const float4*)&Tile[r * 132 + SW(r, c)];
            float4 cv = *(const float4*)&Crow[c];
            float4 cb;
            cb.x = cv.x * b4.x; cb.y = cv.y * b4.y; cb.z = cv.z * b4.z; cb.w = cv.w * b4.w;
            *(float4*)&out[ob + 3 * DL + c] = cb;
        }
    }
}

// ---------------------------------------------------------------------------
extern "C" void kernel_launch(void* const* d_in, const int* in_sizes, int n_in,
                              void* d_out, int out_size, void* d_ws, size_t ws_size,
                              hipStream_t stream) {
    const float* C     = (const float*)d_in[0];
    const float* Q     = (const float*)d_in[1];
    const float* cmask = (const float*)d_in[2];
    const float* qmask = (const float*)d_in[3];
    const float* w     = (const float*)d_in[4];
    float* out = (float*)d_out;

    unsigned short* us = (unsigned short*)d_ws;
    unsigned short* S1b  = us;                                  // B*LC*LQ
    unsigned short* S1Et = S1b  + (size_t)B_ * LC_ * LQ_;       // B*LQ*LC
    unsigned short* CWt  = S1Et + (size_t)B_ * LQ_ * LC_;       // B*LC*D
    unsigned short* Cb   = CWt  + (size_t)B_ * LC_ * D_;        // B*D*LC
    unsigned short* Qt   = Cb   + (size_t)B_ * D_ * LC_;        // B*LQ*D
    unsigned short* Qb   = Qt   + (size_t)B_ * LQ_ * D_;        // B*D*LQ
    unsigned short* T2b  = Qb   + (size_t)B_ * D_ * LQ_;        // B*D*LQ
    float* fp = (float*)(T2b + (size_t)B_ * D_ * LQ_);
    float* T2p    = fp;                                         // 8*B*D*LQ
    float* sc_g   = T2p + (size_t)8 * B_ * D_ * LQ_;            // B*LC
    float* pmax_g = sc_g + (size_t)B_ * LC_;                    // B*32*LQ
    float* psum_g = pmax_g + (size_t)B_ * 32 * LQ_;             // B*32*LQ
    float* sq_g   = psum_g + (size_t)B_ * 32 * LQ_;             // B*LQ
    float* hq_g   = sq_g + (size_t)B_ * LQ_;                    // B*LQ
    float* ci_g   = hq_g + (size_t)B_ * LQ_;                    // B*LQ

    kT_C<<<dim3(LC_ / 32, B_), 256, 0, stream>>>(C, w, CWt, Cb, sc_g);
    kT_Q<<<dim3(LQ_ / 32, B_), 256, 0, stream>>>(Q, w, Qt, Qb, sq_g);
    kA_S<<<dim3(LC_ / 128, B_), 256, 0, stream>>>(CWt, Qt, sc_g, sq_g, cmask, qmask,
                                                  S1b, S1Et, pmax_g, psum_g);
    k2b<<<dim3(B_), 128, 0, stream>>>(pmax_g, psum_g, hq_g, ci_g);
    kB_T2<<<dim3(8, B_), 256, 0, stream>>>(Cb, S1Et, T2p);
    k3b<<<dim3(B_ * D_ * LQ_ / 256), 256, 0, stream>>>(T2p, hq_g, ci_g, T2b);
    kC_out<<<dim3(LC_ / 128, B_), 256, 0, stream>>>(C, Qb, T2b, S1b, out);
}

// Round 5
// 239.588 us; speedup vs baseline: 1.1712x; 1.1712x over previous
//
#include <hip/hip_runtime.h>
#include <cstdint>
#include <cstddef>

#define B_  64
#define D_  128
#define LC_ 1024
#define LQ_ 128
#define NEGV (-1e30f)
#define NINF (-3.402823466e38f)

typedef short s16x8 __attribute__((ext_vector_type(8)));
typedef float f32x4 __attribute__((ext_vector_type(4)));

__device__ __forceinline__ unsigned short f2bf(float x) {
    union { float f; unsigned u; } v; v.f = x;
    unsigned r = v.u + 0x7fffu + ((v.u >> 16) & 1u);   // RNE
    return (unsigned short)(r >> 16);
}

// ---------------------------------------------------------------------------
// kQ: Qt[b][q][d] = bf16(Q[b][d][q]) ; Qb[b][d][q] = bf16(Q) ; sq = sum Q*w_q
// grid (LQ/32, B), 256 thr
// ---------------------------------------------------------------------------
__global__ __launch_bounds__(256) void kQ(const float* __restrict__ Q,
                                          const float* __restrict__ w,
                                          unsigned short* __restrict__ Qt,
                                          unsigned short* __restrict__ Qb,
                                          float* __restrict__ sq_g) {
    __shared__ float tile[32][33];
    __shared__ float wq_l[128];
    __shared__ float red[8][32];
    int t = threadIdx.x;
    int b = blockIdx.y, q0 = blockIdx.x * 32;
    if (t < 128) wq_l[t] = w[t];
    __syncthreads();
    float sqp = 0.f;
    int qq = t & 31, db = t >> 5;
    for (int ch = 0; ch < 4; ch++) {
#pragma unroll
        for (int i = 0; i < 4; i++) {
            int dl = db * 4 + i;
            float v = Q[((size_t)(b * D_ + ch * 32 + dl)) * LQ_ + q0 + qq];
            tile[dl][qq] = v;
            sqp += v * wq_l[ch * 32 + dl];
        }
        __syncthreads();
        {
            int q2 = t >> 3, ds = (t & 7) * 4;
            ushort4 o;
            o.x = f2bf(tile[ds + 0][q2]);
            o.y = f2bf(tile[ds + 1][q2]);
            o.z = f2bf(tile[ds + 2][q2]);
            o.w = f2bf(tile[ds + 3][q2]);
            *(ushort4*)&Qt[((size_t)(b * LQ_ + q0 + q2)) * D_ + ch * 32 + ds] = o;
        }
        {
            int d2 = t >> 3, qs = (t & 7) * 4;
            ushort4 o;
            o.x = f2bf(tile[d2][qs + 0]);
            o.y = f2bf(tile[d2][qs + 1]);
            o.z = f2bf(tile[d2][qs + 2]);
            o.w = f2bf(tile[d2][qs + 3]);
            *(ushort4*)&Qb[((size_t)(b * D_ + ch * 32 + d2)) * LQ_ + q0 + qs] = o;
        }
        __syncthreads();
    }
    red[db][qq] = sqp;
    __syncthreads();
    if (t < 32) {
        float s = 0.f;
#pragma unroll
        for (int j = 0; j < 8; j++) s += red[j][t];
        sq_g[b * LQ_ + q0 + t] = s;
    }
}

// ---------------------------------------------------------------------------
// kS: fused per (b, 128-c-tile):
//   stage C -> LDS CW[c][d] bf16 (+sc);  S = CW x Qt (MFMA) + sc + sq;
//   row softmax -> S1 (bf16 -> S1b), g in registers;
//   col partial stats -> pmax/psum;
//   T2 partial: T2p[tile][b][d][q] = sum_{c in tile} C[d][c] * (S1*g)[c][q]
// grid (LC/128, B), 256 thr
// ---------------------------------------------------------------------------
__global__ __launch_bounds__(256) void kS(const float* __restrict__ C,
                                          const unsigned short* __restrict__ Qt,
                                          const float* __restrict__ w,
                                          const float* __restrict__ sq_g,
                                          const float* __restrict__ cmask,
                                          const float* __restrict__ qmask,
                                          unsigned short* __restrict__ S1b,
                                          float* __restrict__ pmax_g,
                                          float* __restrict__ psum_g,
                                          float* __restrict__ T2p) {
    __shared__ unsigned short CW[128 * 136];   // [c][d] bf16; later reused as S1 [c][q]
    __shared__ unsigned short Tg[128 * 136];   // [q][c] bf16 = S1*g
    __shared__ float stage[32][33];
    __shared__ float wc_l[128], wm_l[128], sq_l[128], cmv_l[128], qmv_l[128], sc_l[128];
    __shared__ float red[8][32];

    int t = threadIdx.x;
    int b = blockIdx.y, c0 = blockIdx.x * 128;
    if (t < 128) {
        wc_l[t] = w[D_ + t];
        wm_l[t] = w[2 * D_ + t];
        sq_l[t] = sq_g[b * LQ_ + t];
        cmv_l[t] = (1.0f - cmask[b * LC_ + c0 + t]) * NEGV;
        qmv_l[t] = (1.0f - qmask[b * LQ_ + t]) * NEGV;
    }
    __syncthreads();

    // ---- stage C tile -> CW[c][d] bf16*wm in LDS; sc = sum_d C*wc ----
    int cc = t & 31, db = t >> 5;
    for (int ch = 0; ch < 4; ch++) {
        float scp = 0.f;
        for (int dh = 0; dh < 4; dh++) {
#pragma unroll
            for (int i = 0; i < 4; i++) {
                int dl = db * 4 + i;
                float v = C[((size_t)(b * D_ + dh * 32 + dl)) * LC_ + c0 + ch * 32 + cc];
                stage[dl][cc] = v;
                scp += v * wc_l[dh * 32 + dl];
            }
            __syncthreads();
            {
                int c2 = t >> 3, ds = (t & 7) * 4;
                ushort4 o;
                o.x = f2bf(stage[ds + 0][c2] * wm_l[dh * 32 + ds + 0]);
                o.y = f2bf(stage[ds + 1][c2] * wm_l[dh * 32 + ds + 1]);
                o.z = f2bf(stage[ds + 2][c2] * wm_l[dh * 32 + ds + 2]);
                o.w = f2bf(stage[ds + 3][c2] * wm_l[dh * 32 + ds + 3]);
                *(ushort4*)&CW[(ch * 32 + c2) * 136 + dh * 32 + ds] = o;
            }
            __syncthreads();
        }
        red[db][cc] = scp;
        __syncthreads();
        if (db == 0) {
            float s = 0.f;
#pragma unroll
            for (int j = 0; j < 8; j++) s += red[j][cc];
            sc_l[ch * 32 + cc] = s;
        }
        __syncthreads();
    }

    // ---- S-MFMA: A from LDS CW, B from global Qt ----
    int wv = t >> 6, l = t & 63, quad = l >> 4, lp = l & 15;
    int w32 = wv * 32;
    f32x4 zero = {0.f, 0.f, 0.f, 0.f};
    f32x4 acc[2][8];
#pragma unroll
    for (int mc = 0; mc < 2; mc++)
#pragma unroll
        for (int qt = 0; qt < 8; qt++) acc[mc][qt] = zero;

#pragma unroll
    for (int ks = 0; ks < 4; ks++) {
        s16x8 a[2], bb[8];
        a[0] = *(const s16x8*)&CW[(w32 + lp) * 136 + ks * 32 + quad * 8];
        a[1] = *(const s16x8*)&CW[(w32 + 16 + lp) * 136 + ks * 32 + quad * 8];
#pragma unroll
        for (int qt = 0; qt < 8; qt++)
            bb[qt] = *(const s16x8*)&Qt[((size_t)(b * LQ_ + qt * 16 + lp)) * D_ + ks * 32 + quad * 8];
#pragma unroll
        for (int mc = 0; mc < 2; mc++)
#pragma unroll
            for (int qt = 0; qt < 8; qt++)
                acc[mc][qt] = __builtin_amdgcn_mfma_f32_16x16x32_bf16(a[mc], bb[qt], acc[mc][qt], 0, 0, 0);
    }
#pragma unroll
    for (int mc = 0; mc < 2; mc++)
#pragma unroll
        for (int qt = 0; qt < 8; qt++)
#pragma unroll
            for (int i = 0; i < 4; i++)
                acc[mc][qt][i] += sc_l[w32 + mc * 16 + quad * 4 + i] + sq_l[qt * 16 + lp];

    float qmv_r[8];
#pragma unroll
    for (int qt = 0; qt < 8; qt++) qmv_r[qt] = qmv_l[qt * 16 + lp];

    // ---- row softmax (over q); g kept in registers (all lanes have butterfly) ----
    float rm_r[2][4], ri_r[2][4], gs_r[2][4];
#pragma unroll
    for (int mc = 0; mc < 2; mc++)
#pragma unroll
        for (int i = 0; i < 4; i++) {
            int row = w32 + mc * 16 + quad * 4 + i;
            float m = NINF;
#pragma unroll
            for (int qt = 0; qt < 8; qt++) m = fmaxf(m, acc[mc][qt][i] + qmv_r[qt]);
#pragma unroll
            for (int off = 1; off < 16; off <<= 1) m = fmaxf(m, __shfl_xor(m, off, 64));
            float s = 0.f;
#pragma unroll
            for (int qt = 0; qt < 8; qt++) s += __expf(acc[mc][qt][i] + qmv_r[qt] - m);
#pragma unroll
            for (int off = 1; off < 16; off <<= 1) s += __shfl_xor(s, off, 64);
            rm_r[mc][i] = m;
            ri_r[mc][i] = 1.0f / s;
            gs_r[mc][i] = s * __expf(m + cmv_l[row]);
        }

    // ---- column partial stats over this wave's 32 rows ----
    float cmv_r[2][4];
#pragma unroll
    for (int mc = 0; mc < 2; mc++)
#pragma unroll
        for (int i = 0; i < 4; i++) cmv_r[mc][i] = cmv_l[w32 + mc * 16 + quad * 4 + i];
    int chunk = blockIdx.x * 4 + wv;
#pragma unroll
    for (int qt = 0; qt < 8; qt++) {
        float cm = NINF;
#pragma unroll
        for (int mc = 0; mc < 2; mc++)
#pragma unroll
            for (int i = 0; i < 4; i++) cm = fmaxf(cm, acc[mc][qt][i] + cmv_r[mc][i]);
        cm = fmaxf(cm, __shfl_xor(cm, 16, 64));
        cm = fmaxf(cm, __shfl_xor(cm, 32, 64));
        float cs = 0.f;
#pragma unroll
        for (int mc = 0; mc < 2; mc++)
#pragma unroll
            for (int i = 0; i < 4; i++) cs += __expf(acc[mc][qt][i] + cmv_r[mc][i] - cm);
        cs += __shfl_xor(cs, 16, 64);
        cs += __shfl_xor(cs, 32, 64);
        if (l < 16) {
            pmax_g[((size_t)(b * 32 + chunk)) * LQ_ + qt * 16 + lp] = cm;
            psum_g[((size_t)(b * 32 + chunk)) * LQ_ + qt * 16 + lp] = cs;
        }
    }

    // ---- S1 -> CW (as [c][q]); S1*g -> Tg (as [q][c]) ----
    __syncthreads();   // all A-fragment reads of CW are done
#pragma unroll
    for (int mc = 0; mc < 2; mc++)
#pragma unroll
        for (int qt = 0; qt < 8; qt++)
#pragma unroll
            for (int i = 0; i < 4; i++) {
                int row = w32 + mc * 16 + quad * 4 + i;
                int q = qt * 16 + lp;
                float s1 = __expf(acc[mc][qt][i] + qmv_r[qt] - rm_r[mc][i]) * ri_r[mc][i];
                CW[row * 136 + q] = f2bf(s1);
                Tg[q * 136 + row] = f2bf(s1 * gs_r[mc][i]);
            }
    __syncthreads();

    // ---- S1b copy-out (coalesced) ----
    {
        int row = t >> 1, qh = (t & 1) * 64;
        const uint4* src = (const uint4*)&CW[row * 136 + qh];
        uint4* dst = (uint4*)&S1b[((size_t)(b * LC_ + c0 + row)) * LQ_ + qh];
#pragma unroll
        for (int j = 0; j < 8; j++) dst[j] = src[j];
    }

    // ---- T2 partial GEMM: A = C (fp32->bf16 direct), B = Tg ----
    f32x4 acc2[2][8];
#pragma unroll
    for (int mc = 0; mc < 2; mc++)
#pragma unroll
        for (int nt = 0; nt < 8; nt++) acc2[mc][nt] = zero;
#pragma unroll
    for (int ks = 0; ks < 4; ks++) {
        s16x8 a2[2], bb[8];
#pragma unroll
        for (int m = 0; m < 2; m++) {
            int d = w32 + m * 16 + lp;
            const float4* p = (const float4*)&C[((size_t)(b * D_ + d)) * LC_ + c0 + ks * 32 + quad * 8];
            float4 v0 = p[0], v1 = p[1];
            unsigned short* pp = (unsigned short*)&a2[m];
            pp[0] = f2bf(v0.x); pp[1] = f2bf(v0.y); pp[2] = f2bf(v0.z); pp[3] = f2bf(v0.w);
            pp[4] = f2bf(v1.x); pp[5] = f2bf(v1.y); pp[6] = f2bf(v1.z); pp[7] = f2bf(v1.w);
        }
#pragma unroll
        for (int nt = 0; nt < 8; nt++)
            bb[nt] = *(const s16x8*)&Tg[(nt * 16 + lp) * 136 + ks * 32 + quad * 8];
#pragma unroll
        for (int m = 0; m < 2; m++)
#pragma unroll
            for (int nt = 0; nt < 8; nt++)
                acc2[m][nt] = __builtin_amdgcn_mfma_f32_16x16x32_bf16(a2[m], bb[nt], acc2[m][nt], 0, 0, 0);
    }
    size_t base = ((size_t)(blockIdx.x * B_ + b)) * ((size_t)D_ * LQ_);
#pragma unroll
    for (int mc = 0; mc < 2; mc++)
#pragma unroll
        for (int i = 0; i < 4; i++) {
            int d = w32 + mc * 16 + quad * 4 + i;
#pragma unroll
            for (int nt = 0; nt < 8; nt++)
                T2p[base + (size_t)d * LQ_ + nt * 16 + lp] = acc2[mc][nt][i];
        }
}

// ---------------------------------------------------------------------------
// k2b: reduce 32 col-partial chunks -> hq = exp(-colmax), ci = 1/colsum
// ---------------------------------------------------------------------------
__global__ __launch_bounds__(128) void k2b(const float* __restrict__ pmax,
                                           const float* __restrict__ psum,
                                           float* __restrict__ hq_g,
                                           float* __restrict__ ci_g) {
    int q = threadIdx.x, b = blockIdx.x;
    float m = NINF;
    for (int j = 0; j < 32; j++) m = fmaxf(m, pmax[((size_t)(b * 32 + j)) * LQ_ + q]);
    float s = 0.f;
    for (int j = 0; j < 32; j++)
        s += psum[((size_t)(b * 32 + j)) * LQ_ + q] * __expf(pmax[((size_t)(b * 32 + j)) * LQ_ + q] - m);
    hq_g[b * LQ_ + q] = __expf(-m);
    ci_g[b * LQ_ + q] = 1.0f / s;
}

// ---------------------------------------------------------------------------
// k3b: T2b bf16 = (sum of 8 c-tile partials) * hq[q] * ci[q]
// ---------------------------------------------------------------------------
__global__ __launch_bounds__(256) void k3b(const float* __restrict__ T2p,
                                           const float* __restrict__ hq_g,
                                           const float* __restrict__ ci_g,
                                           unsigned short* __restrict__ T2b) {
    int idx = blockIdx.x * 256 + threadIdx.x;
    const size_t N = (size_t)B_ * D_ * LQ_;
    int b = idx >> 14, q = idx & 127;
    float s = 0.f;
#pragma unroll
    for (int j = 0; j < 8; j++) s += T2p[(size_t)j * N + idx];
    T2b[idx] = f2bf(s * hq_g[b * LQ_ + q] * ci_g[b * LQ_ + q]);
}

// ---------------------------------------------------------------------------
// kC_out: accA = S1·Q^T, accB = S1·T2^T, LDS-free, direct scalar stores
// (wave covers 4 d-rows x 16 consecutive c per store -> full 64B segments).
// grid (LC/64, B), 256 thr
// ---------------------------------------------------------------------------
__global__ __launch_bounds__(256) void kC_out(const float* __restrict__ C,
                                              const unsigned short* __restrict__ Qb,
                                              const unsigned short* __restrict__ T2b,
                                              const unsigned short* __restrict__ S1b,
                                              float* __restrict__ out) {
    int t = threadIdx.x;
    int b = blockIdx.y, c0 = blockIdx.x * 64;
    int wv = t >> 6, l = t & 63, quad = l >> 4, lp = l & 15;
    int w32 = wv * 32;
    f32x4 zero = {0.f, 0.f, 0.f, 0.f};
    f32x4 accA[2][4], accB[2][4];
#pragma unroll
    for (int mc = 0; mc < 2; mc++)
#pragma unroll
        for (int nt = 0; nt < 4; nt++) { accA[mc][nt] = zero; accB[mc][nt] = zero; }

#pragma unroll
    for (int ks = 0; ks < 4; ks++) {
        s16x8 aq[2], at[2], bb[4];
        aq[0] = *(const s16x8*)&Qb[((size_t)(b * D_ + w32 + lp)) * LQ_ + ks * 32 + quad * 8];
        aq[1] = *(const s16x8*)&Qb[((size_t)(b * D_ + w32 + 16 + lp)) * LQ_ + ks * 32 + quad * 8];
        at[0] = *(const s16x8*)&T2b[((size_t)(b * D_ + w32 + lp)) * LQ_ + ks * 32 + quad * 8];
        at[1] = *(const s16x8*)&T2b[((size_t)(b * D_ + w32 + 16 + lp)) * LQ_ + ks * 32 + quad * 8];
#pragma unroll
        for (int nt = 0; nt < 4; nt++)
            bb[nt] = *(const s16x8*)&S1b[((size_t)(b * LC_ + c0 + nt * 16 + lp)) * LQ_ + ks * 32 + quad * 8];
#pragma unroll
        for (int mc = 0; mc < 2; mc++)
#pragma unroll
            for (int nt = 0; nt < 4; nt++) {
                accA[mc][nt] = __builtin_amdgcn_mfma_f32_16x16x32_bf16(aq[mc], bb[nt], accA[mc][nt], 0, 0, 0);
                accB[mc][nt] = __builtin_amdgcn_mfma_f32_16x16x32_bf16(at[mc], bb[nt], accB[mc][nt], 0, 0, 0);
            }
    }
    const size_t DL = (size_t)D_ * LC_;
#pragma unroll
    for (int mc = 0; mc < 2; mc++)
#pragma unroll
        for (int i = 0; i < 4; i++) {
            int d = w32 + mc * 16 + quad * 4 + i;
            const float* Crow = C + ((size_t)(b * D_ + d)) * LC_ + c0;
            size_t ob = ((size_t)(b * 4 * D_ + d)) * LC_ + c0;
#pragma unroll
            for (int nt = 0; nt < 4; nt++) {
                int c = nt * 16 + lp;
                float cv = Crow[c];
                float a = accA[mc][nt][i];
                float bt = accB[mc][nt][i];
                out[ob + c] = cv;
                out[ob + DL + c] = a;
                out[ob + 2 * DL + c] = cv * a;
                out[ob + 3 * DL + c] = cv * bt;
            }
        }
}

// ---------------------------------------------------------------------------
extern "C" void kernel_launch(void* const* d_in, const int* in_sizes, int n_in,
                              void* d_out, int out_size, void* d_ws, size_t ws_size,
                              hipStream_t stream) {
    const float* C     = (const float*)d_in[0];
    const float* Q     = (const float*)d_in[1];
    const float* cmask = (const float*)d_in[2];
    const float* qmask = (const float*)d_in[3];
    const float* w     = (const float*)d_in[4];
    float* out = (float*)d_out;

    unsigned short* us = (unsigned short*)d_ws;
    unsigned short* S1b = us;                                   // B*LC*LQ
    unsigned short* Qt  = S1b + (size_t)B_ * LC_ * LQ_;         // B*LQ*D
    unsigned short* Qb  = Qt  + (size_t)B_ * LQ_ * D_;          // B*D*LQ
    unsigned short* T2b = Qb  + (size_t)B_ * D_ * LQ_;          // B*D*LQ
    float* fp = (float*)(T2b + (size_t)B_ * D_ * LQ_);
    float* T2p    = fp;                                         // 8*B*D*LQ
    float* pmax_g = T2p + (size_t)8 * B_ * D_ * LQ_;            // B*32*LQ
    float* psum_g = pmax_g + (size_t)B_ * 32 * LQ_;             // B*32*LQ
    float* sq_g   = psum_g + (size_t)B_ * 32 * LQ_;             // B*LQ
    float* hq_g   = sq_g + (size_t)B_ * LQ_;                    // B*LQ
    float* ci_g   = hq_g + (size_t)B_ * LQ_;                    // B*LQ

    kQ<<<dim3(LQ_ / 32, B_), 256, 0, stream>>>(Q, w, Qt, Qb, sq_g);
    kS<<<dim3(LC_ / 128, B_), 256, 0, stream>>>(C, Qt, w, sq_g, cmask, qmask,
                                                S1b, pmax_g, psum_g, T2p);
    k2b<<<dim3(B_), 128, 0, stream>>>(pmax_g, psum_g, hq_g, ci_g);
    k3b<<<dim3(B_ * D_ * LQ_ / 256), 256, 0, stream>>>(T2p, hq_g, ci_g, T2b);
    kC_out<<<dim3(LC_ / 64, B_), 256, 0, stream>>>(C, Qb, T2b, S1b, out);
}